// Round 7
// baseline (318.547 us; speedup 1.0000x reference)
//
#include <hip/hip_runtime.h>

// Problem constants (match reference setup_inputs()).
constexpr int B = 4, C = 8, H = 160, W = 160, Dd = 160, NPER = 100000;
constexpr long HWD = (long)H * W * Dd;            // 4,096,000 voxels per image
constexpr int  TOTAL_PTS = NPER * B;              // 400,000 (point, image) pairs
constexpr int  TOTAL_OUT = NPER * B * C;          // 3,200,000 output elements

constexpr int  TS   = 8;                          // tile edge (voxels)
constexpr int  TDIM = H / TS;                     // 20 tiles per axis
constexpr int  NT   = B * TDIM * TDIM;            // 1600 tiles
constexpr int  HC   = TS + 1;                     // halo columns per axis = 9
constexpr int  ZV4  = Dd / 4;                     // 40 float4 per z-column
constexpr int  NLOAD = HC * HC * ZV4;             // 3240 float4 per halo

typedef float f32x4 __attribute__((ext_vector_type(4)));

// Workspace layout (bytes).
constexpr size_t WS_CURSOR_OFF = 0;                          // NT*4
constexpr size_t WS_OFFS_OFF   = 8192;                       // (NT+1)*4
constexpr size_t WS_PAY_OFF    = 16384;                      // 16B records
constexpr size_t WS_NEEDED     = WS_PAY_OFF + (size_t)TOTAL_PTS * 16;

__device__ __forceinline__ float load_image_dim(const int* dimp) {
    int iv = dimp[0];
    return (iv > 0 && iv < 1000000) ? (float)iv : __int_as_float(iv);
}

struct Coord {
    int x1, x2, y1, y2, z1, z2;
    float wx, wx2, wy, wy2, wz, wz2;
};
// Must be bit-identical in hist / scatter / gather.
__device__ __forceinline__ Coord coord_from_xyz(float gx, float gy, float gz,
                                                float factor) {
    Coord c;
    float x = gx / factor, y = gy / factor, z = gz / factor;
    float x1f = fminf(floorf(x), (float)(H - 1));
    float x2f = fminf(ceilf(x),  (float)(H - 1));
    float y1f = fminf(floorf(y), (float)(W - 1));
    float y2f = fminf(ceilf(y),  (float)(W - 1));
    float z1f = fminf(floorf(z), (float)(Dd - 1));
    float z2f = fminf(ceilf(z),  (float)(Dd - 1));
    c.x1 = max(0, (int)x1f); c.x2 = max(0, (int)x2f);
    c.y1 = max(0, (int)y1f); c.y2 = max(0, (int)y2f);
    c.z1 = max(0, (int)z1f); c.z2 = max(0, (int)z2f);
    c.wx = x - x1f; c.wx2 = x2f - x;
    c.wy = y - y1f; c.wy2 = y2f - y;
    c.wz = z - z1f; c.wz2 = z2f - z;
    return c;
}

__device__ __forceinline__ int tile_key(int b, const Coord& c) {
    return (b * TDIM + (c.x1 >> 3)) * TDIM + (c.y1 >> 3);
}

// --------------------------- bucketing machinery ---------------------------
__global__ __launch_bounds__(256) void zero_kernel(int* __restrict__ cursor) {
    int i = blockIdx.x * 256 + threadIdx.x;
    if (i < NT) cursor[i] = 0;
}

__global__ __launch_bounds__(256) void hist_kernel(
    const float* __restrict__ gf, const int* __restrict__ dimp,
    int* __restrict__ cursor)
{
    int p = blockIdx.x * 256 + threadIdx.x;
    if (p >= TOTAL_PTS) return;
    float factor = load_image_dim(dimp) / (float)H;
    int b = p / NPER;
    Coord c = coord_from_xyz(gf[(long)p*3], gf[(long)p*3+1], gf[(long)p*3+2], factor);
    atomicAdd(&cursor[tile_key(b, c)], 1);
}

// Single-block exclusive scan over NT=1600 counts -> offsets + cursor init.
__global__ __launch_bounds__(512) void scan_kernel(
    int* __restrict__ cursor, int* __restrict__ offsets)
{
    constexpr int CH = (NT + 511) / 512;   // 4
    __shared__ int sm[512];
    int t = threadIdx.x;
    int loc[CH];
    int s = 0;
    #pragma unroll
    for (int k = 0; k < CH; ++k) {
        int g = t * CH + k;
        int v = (g < NT) ? cursor[g] : 0;
        loc[k] = v; s += v;
    }
    sm[t] = s;
    __syncthreads();
    for (int off = 1; off < 512; off <<= 1) {
        int u = (t >= off) ? sm[t - off] : 0;
        __syncthreads();
        sm[t] += u;
        __syncthreads();
    }
    int run = sm[t] - s;                   // exclusive prefix of this chunk
    #pragma unroll
    for (int k = 0; k < CH; ++k) {
        int g = t * CH + k;
        if (g < NT) { offsets[g] = run; cursor[g] = run; run += loc[k]; }
    }
    if (t == 511) offsets[NT] = sm[511];
}

// Scatter payload {p_bits, gx, gy, gz} into tile-grouped order.
__global__ __launch_bounds__(256) void scatter_kernel(
    const float* __restrict__ gf, const int* __restrict__ dimp,
    int* __restrict__ cursor, f32x4* __restrict__ payload)
{
    int p = blockIdx.x * 256 + threadIdx.x;
    if (p >= TOTAL_PTS) return;
    float factor = load_image_dim(dimp) / (float)H;
    int b = p / NPER;
    float gx = gf[(long)p*3], gy = gf[(long)p*3+1], gz = gf[(long)p*3+2];
    Coord c = coord_from_xyz(gx, gy, gz, factor);
    int pos = atomicAdd(&cursor[tile_key(b, c)], 1);
    f32x4 rec;
    rec.x = __int_as_float(p); rec.y = gx; rec.z = gy; rec.w = gz;
    payload[pos] = rec;
}

// --------------------------- tiled gather (one channel per block) ----------
// Block = (tile, channel). Load the 9x9 halo of full z-columns for ONE
// channel into LDS (coalesced float4, single barrier), then tap points.
// 12,800 blocks x 3 resident/CU gives the TLP round 6 lacked.
__global__ __launch_bounds__(512) void gather_tiled(
    const float* __restrict__ img, const f32x4* __restrict__ payload,
    const int* __restrict__ offsets, const int* __restrict__ dimp,
    float* __restrict__ out)
{
    // Chunked bijective XCD swizzle (nwg = NT*8, divisible by 8): the 8
    // channel-blocks of a tile stay in one XCD chunk -> payload L2 reuse.
    int nwg = gridDim.x;
    int q = nwg >> 3;
    int wg = (blockIdx.x & 7) * q + (blockIdx.x >> 3);

    int tile = wg >> 3;
    int c    = wg & 7;
    int ty = tile % TDIM;
    int tx = (tile / TDIM) % TDIM;
    int b  = tile / (TDIM * TDIM);
    int beg = offsets[tile], end = offsets[tile + 1];
    if (beg == end) return;

    int x0 = tx * TS, y0 = ty * TS;
    __shared__ float lds[HC * HC * Dd];    // 51,840 B -> 3 blocks/CU

    const float* chbase = img + (long)(b * C + c) * HWD;
    int tid = threadIdx.x;

    #pragma unroll 2
    for (int l = tid; l < NLOAD; l += 512) {
        int col = l / ZV4, qq = l - col * ZV4;
        int cx = col / HC, cy = col - cx * HC;
        int x = min(x0 + cx, H - 1), y = min(y0 + cy, W - 1);
        const f32x4* src = reinterpret_cast<const f32x4*>(
            chbase + ((long)x * W + y) * Dd) + qq;
        *reinterpret_cast<f32x4*>(&lds[col * Dd + qq * 4]) = *src;
    }
    __syncthreads();

    float factor = load_image_dim(dimp) / (float)H;
    for (int i = beg + tid; i < end; i += 512) {
        f32x4 rec = payload[i];
        int p = __float_as_int(rec.x);
        int j = p - b * NPER;
        Coord cc = coord_from_xyz(rec.y, rec.z, rec.w, factor);

        int i11 = ((cc.x1 - x0) * HC + (cc.y1 - y0)) * Dd;
        int i12 = ((cc.x1 - x0) * HC + (cc.y2 - y0)) * Dd;
        int i21 = ((cc.x2 - x0) * HC + (cc.y1 - y0)) * Dd;
        int i22 = ((cc.x2 - x0) * HC + (cc.y2 - y0)) * Dd;

        float lx1_a = lds[i21 + cc.z2] * cc.wx + lds[i11 + cc.z2] * cc.wx2;
        float lx2_a = lds[i22 + cc.z2] * cc.wx + lds[i12 + cc.z2] * cc.wx2;
        float ly_a  = lx2_a * cc.wy + lx1_a * cc.wy2;
        float lx1_b = lds[i21 + cc.z1] * cc.wx + lds[i11 + cc.z1] * cc.wx2;
        float lx2_b = lds[i22 + cc.z1] * cc.wx + lds[i12 + cc.z1] * cc.wx2;
        float ly_b  = lx2_b * cc.wy + lx1_b * cc.wy2;
        float res   = ly_a * cc.wz + ly_b * cc.wz2;

        __builtin_nontemporal_store(res, out + (long)j * 32 + b * 8 + c);
    }
}

// --------------------------- fallback (unsorted direct) --------------------
__global__ __launch_bounds__(256) void og_proj_direct(
    const float* __restrict__ img, const float* __restrict__ gf,
    const int* __restrict__ dimp, float* __restrict__ out)
{
    int o = blockIdx.x * 256 + threadIdx.x;
    if (o >= TOTAL_OUT) return;
    int j = o >> 5, bc = o & 31, b = bc >> 3, c = bc & 7;
    float factor = load_image_dim(dimp) / (float)H;
    long p = (long)b * NPER + j;
    Coord cc = coord_from_xyz(gf[p*3], gf[p*3+1], gf[p*3+2], factor);

    const float* base = img + (size_t)(b * C + c) * (size_t)HWD;
    size_t r11 = ((size_t)cc.x1 * W + cc.y1) * Dd;
    size_t r12 = ((size_t)cc.x1 * W + cc.y2) * Dd;
    size_t r21 = ((size_t)cc.x2 * W + cc.y1) * Dd;
    size_t r22 = ((size_t)cc.x2 * W + cc.y2) * Dd;

    float lx1_a = base[r21 + cc.z2] * cc.wx + base[r11 + cc.z2] * cc.wx2;
    float lx2_a = base[r22 + cc.z2] * cc.wx + base[r12 + cc.z2] * cc.wx2;
    float ly_a  = lx2_a * cc.wy + lx1_a * cc.wy2;
    float lx1_b = base[r21 + cc.z1] * cc.wx + base[r11 + cc.z1] * cc.wx2;
    float lx2_b = base[r22 + cc.z1] * cc.wx + base[r12 + cc.z1] * cc.wx2;
    float ly_b  = lx2_b * cc.wy + lx1_b * cc.wy2;
    out[o] = ly_a * cc.wz + ly_b * cc.wz2;
}

extern "C" void kernel_launch(void* const* d_in, const int* in_sizes, int n_in,
                              void* d_out, int out_size, void* d_ws, size_t ws_size,
                              hipStream_t stream) {
    const float* img  = (const float*)d_in[0];
    const float* gf   = (const float*)d_in[1];
    const int*   dimp = (const int*)d_in[3];
    float* out = (float*)d_out;

    if (ws_size >= WS_NEEDED) {
        int*   cursor  = (int*)((char*)d_ws + WS_CURSOR_OFF);
        int*   offsets = (int*)((char*)d_ws + WS_OFFS_OFF);
        f32x4* payld   = (f32x4*)((char*)d_ws + WS_PAY_OFF);

        int pblocks = (TOTAL_PTS + 255) / 256;       // 1563
        zero_kernel<<<(NT + 255) / 256, 256, 0, stream>>>(cursor);
        hist_kernel<<<pblocks, 256, 0, stream>>>(gf, dimp, cursor);
        scan_kernel<<<1, 512, 0, stream>>>(cursor, offsets);
        scatter_kernel<<<pblocks, 256, 0, stream>>>(gf, dimp, cursor, payld);
        gather_tiled<<<NT * 8, 512, 0, stream>>>(img, payld, offsets, dimp, out);
    } else {
        int blocks = (TOTAL_OUT + 255) / 256;
        og_proj_direct<<<blocks, 256, 0, stream>>>(img, gf, dimp, out);
    }
}

// Round 8
// 199.807 us; speedup vs baseline: 1.5943x; 1.5943x over previous
//
#include <hip/hip_runtime.h>

// Problem constants (match reference setup_inputs()).
constexpr int B = 4, C = 8, H = 160, W = 160, Dd = 160, NPER = 100000;
constexpr long HWD = (long)H * W * Dd;            // 4,096,000 voxels per image
constexpr int  TOTAL_PTS = NPER * B;              // 400,000 (point, image) pairs
constexpr int  TOTAL_OUT = NPER * B * C;          // 3,200,000 output elements
constexpr int  NKEYS = B * H * W;                 // 102,400 (b, x1, y1) buckets
constexpr int  SCAN_BLOCKS = NKEYS / 256;         // 400

typedef float f32x4 __attribute__((ext_vector_type(4)));

// Workspace layout (bytes) — only sort scratch (~7 MB).
constexpr size_t WS_COUNTS_OFF = 0;
constexpr size_t WS_PART_OFF   = (size_t)NKEYS * 4;          // 409,600
constexpr size_t WS_PAY_OFF    = WS_PART_OFF + 4096;         // 16B-aligned
constexpr size_t WS_NEEDED     = WS_PAY_OFF + (size_t)TOTAL_PTS * 16;

__device__ __forceinline__ float load_image_dim(const int* dimp) {
    int iv = dimp[0];
    return (iv > 0 && iv < 1000000) ? (float)iv : __int_as_float(iv);
}

struct Coord {
    int x1, x2, y1, y2, z1, z2;
    float wx, wx2, wy, wy2, wz, wz2;
};
// Must be bit-identical in hist / scatter / gather.
__device__ __forceinline__ Coord coord_from_xyz(float gx, float gy, float gz,
                                                float factor) {
    Coord c;
    float x = gx / factor, y = gy / factor, z = gz / factor;
    float x1f = fminf(floorf(x), (float)(H - 1));
    float x2f = fminf(ceilf(x),  (float)(H - 1));
    float y1f = fminf(floorf(y), (float)(W - 1));
    float y2f = fminf(ceilf(y),  (float)(W - 1));
    float z1f = fminf(floorf(z), (float)(Dd - 1));
    float z2f = fminf(ceilf(z),  (float)(Dd - 1));
    c.x1 = max(0, (int)x1f); c.x2 = max(0, (int)x2f);
    c.y1 = max(0, (int)y1f); c.y2 = max(0, (int)y2f);
    c.z1 = max(0, (int)z1f); c.z2 = max(0, (int)z2f);
    c.wx = x - x1f; c.wx2 = x2f - x;
    c.wy = y - y1f; c.wy2 = y2f - y;
    c.wz = z - z1f; c.wz2 = z2f - z;
    return c;
}

// --------------------------- sort machinery --------------------------------
__global__ __launch_bounds__(256) void zero_kernel(int* __restrict__ counts) {
    int i = blockIdx.x * 256 + threadIdx.x;
    if (i < NKEYS) counts[i] = 0;
}

__global__ __launch_bounds__(256) void hist_kernel(
    const float* __restrict__ gf, const int* __restrict__ dimp,
    int* __restrict__ counts)
{
    int p = blockIdx.x * 256 + threadIdx.x;
    if (p >= TOTAL_PTS) return;
    float factor = load_image_dim(dimp) / (float)H;
    int b = p / NPER;
    Coord c = coord_from_xyz(gf[(long)p*3], gf[(long)p*3+1], gf[(long)p*3+2], factor);
    atomicAdd(&counts[(b * H + c.x1) * W + c.y1], 1);
}

__global__ __launch_bounds__(256) void scanA_kernel(
    int* __restrict__ counts, int* __restrict__ partials)
{
    __shared__ int sm[256];
    int g = blockIdx.x * 256 + threadIdx.x;
    int v = counts[g];
    sm[threadIdx.x] = v;
    __syncthreads();
    for (int off = 1; off < 256; off <<= 1) {
        int t = (threadIdx.x >= off) ? sm[threadIdx.x - off] : 0;
        __syncthreads();
        sm[threadIdx.x] += t;
        __syncthreads();
    }
    counts[g] = sm[threadIdx.x] - v;                 // exclusive within block
    if (threadIdx.x == 255) partials[blockIdx.x] = sm[255];
}

__global__ __launch_bounds__(512) void scanB_kernel(int* __restrict__ partials)
{
    __shared__ int sm[512];
    int t = threadIdx.x;
    int v = (t < SCAN_BLOCKS) ? partials[t] : 0;
    sm[t] = v;
    __syncthreads();
    for (int off = 1; off < 512; off <<= 1) {
        int u = (t >= off) ? sm[t - off] : 0;
        __syncthreads();
        sm[t] += u;
        __syncthreads();
    }
    if (t < SCAN_BLOCKS) partials[t] = sm[t] - v;    // exclusive
}

__global__ __launch_bounds__(256) void scanC_kernel(
    int* __restrict__ counts, const int* __restrict__ partials)
{
    int g = blockIdx.x * 256 + threadIdx.x;
    counts[g] += partials[blockIdx.x];
}

// Scatter payload {p_bits, gx, gy, gz} into sorted position.
__global__ __launch_bounds__(256) void scatter_kernel(
    const float* __restrict__ gf, const int* __restrict__ dimp,
    int* __restrict__ counts, f32x4* __restrict__ payload)
{
    int p = blockIdx.x * 256 + threadIdx.x;
    if (p >= TOTAL_PTS) return;
    float factor = load_image_dim(dimp) / (float)H;
    int b = p / NPER;
    float gx = gf[(long)p*3], gy = gf[(long)p*3+1], gz = gf[(long)p*3+2];
    Coord c = coord_from_xyz(gx, gy, gz, factor);
    int pos = atomicAdd(&counts[(b * H + c.x1) * W + c.y1], 1);
    f32x4 rec;
    rec.x = __int_as_float(p); rec.y = gx; rec.z = gy; rec.w = gz;
    payload[pos] = rec;
}

// --------------------------- sorted direct gather (thread = point) ---------
// One thread per sorted point; loop over the 8 channels inside the thread.
// Per load instruction a wave issues the SAME tap for 64 sorted points ->
// same-bucket lanes merge to identical lines, and the ~16 unique lines fall
// in a 10-20 KB window of ONE channel slab (3 columns per 2 KB DRAM row) ->
// row-buffer hits instead of random 64 B activations.
__global__ __launch_bounds__(256) void gather_sorted_pt(
    const float* __restrict__ img, const f32x4* __restrict__ payload,
    const int* __restrict__ dimp, float* __restrict__ out)
{
    // Bijective chunked XCD swizzle: consecutive sorted ranges share an XCD.
    int nwg = gridDim.x;
    int q = nwg >> 3, r = nwg & 7;
    int xcd = blockIdx.x & 7, idx = blockIdx.x >> 3;
    int wg = (xcd < r) ? xcd * (q + 1) + idx
                       : r * (q + 1) + (xcd - r) * q + idx;
    int i = wg * 256 + threadIdx.x;
    if (i >= TOTAL_PTS) return;

    f32x4 rec = payload[i];
    int p = __float_as_int(rec.x);
    int b = p / NPER;
    int j = p - b * NPER;

    float factor = load_image_dim(dimp) / (float)H;
    Coord cc = coord_from_xyz(rec.y, rec.z, rec.w, factor);

    long o11 = ((long)cc.x1 * W + cc.y1) * Dd;
    long o12 = ((long)cc.x1 * W + cc.y2) * Dd;
    long o21 = ((long)cc.x2 * W + cc.y1) * Dd;
    long o22 = ((long)cc.x2 * W + cc.y2) * Dd;
    const float* base0 = img + (long)b * C * HWD;

    float res[8];
    #pragma unroll
    for (int c = 0; c < 8; ++c) {
        const float* bc = base0 + (long)c * HWD;
        float v11a = bc[o11 + cc.z2], v12a = bc[o12 + cc.z2];
        float v21a = bc[o21 + cc.z2], v22a = bc[o22 + cc.z2];
        float v11b = bc[o11 + cc.z1], v12b = bc[o12 + cc.z1];
        float v21b = bc[o21 + cc.z1], v22b = bc[o22 + cc.z1];
        float lx1_a = v21a * cc.wx + v11a * cc.wx2;
        float lx2_a = v22a * cc.wx + v12a * cc.wx2;
        float ly_a  = lx2_a * cc.wy + lx1_a * cc.wy2;
        float lx1_b = v21b * cc.wx + v11b * cc.wx2;
        float lx2_b = v22b * cc.wx + v12b * cc.wx2;
        float ly_b  = lx2_b * cc.wy + lx1_b * cc.wy2;
        res[c] = ly_a * cc.wz + ly_b * cc.wz2;
    }

    // Grouped 32 B store per point; consecutive lanes = consecutive sorted
    // points -> full-line write combining.
    f32x4 r0, r1;
    r0[0] = res[0]; r0[1] = res[1]; r0[2] = res[2]; r0[3] = res[3];
    r1[0] = res[4]; r1[1] = res[5]; r1[2] = res[6]; r1[3] = res[7];
    float* dst = out + (long)j * 32 + b * 8;
    __builtin_nontemporal_store(r0, reinterpret_cast<f32x4*>(dst));
    __builtin_nontemporal_store(r1, reinterpret_cast<f32x4*>(dst + 4));
}

// --------------------------- fallback (unsorted direct) --------------------
__global__ __launch_bounds__(256) void og_proj_direct(
    const float* __restrict__ img, const float* __restrict__ gf,
    const int* __restrict__ dimp, float* __restrict__ out)
{
    int o = blockIdx.x * 256 + threadIdx.x;
    if (o >= TOTAL_OUT) return;
    int j = o >> 5, bc = o & 31, b = bc >> 3, c = bc & 7;
    float factor = load_image_dim(dimp) / (float)H;
    long p = (long)b * NPER + j;
    Coord cc = coord_from_xyz(gf[p*3], gf[p*3+1], gf[p*3+2], factor);

    const float* base = img + (size_t)(b * C + c) * (size_t)HWD;
    size_t r11 = ((size_t)cc.x1 * W + cc.y1) * Dd;
    size_t r12 = ((size_t)cc.x1 * W + cc.y2) * Dd;
    size_t r21 = ((size_t)cc.x2 * W + cc.y1) * Dd;
    size_t r22 = ((size_t)cc.x2 * W + cc.y2) * Dd;

    float lx1_a = base[r21 + cc.z2] * cc.wx + base[r11 + cc.z2] * cc.wx2;
    float lx2_a = base[r22 + cc.z2] * cc.wx + base[r12 + cc.z2] * cc.wx2;
    float ly_a  = lx2_a * cc.wy + lx1_a * cc.wy2;
    float lx1_b = base[r21 + cc.z1] * cc.wx + base[r11 + cc.z1] * cc.wx2;
    float lx2_b = base[r22 + cc.z1] * cc.wx + base[r12 + cc.z1] * cc.wx2;
    float ly_b  = lx2_b * cc.wy + lx1_b * cc.wy2;
    out[o] = ly_a * cc.wz + ly_b * cc.wz2;
}

extern "C" void kernel_launch(void* const* d_in, const int* in_sizes, int n_in,
                              void* d_out, int out_size, void* d_ws, size_t ws_size,
                              hipStream_t stream) {
    const float* img  = (const float*)d_in[0];
    const float* gf   = (const float*)d_in[1];
    const int*   dimp = (const int*)d_in[3];
    float* out = (float*)d_out;

    if (ws_size >= WS_NEEDED) {
        int*   counts = (int*)((char*)d_ws + WS_COUNTS_OFF);
        int*   parts  = (int*)((char*)d_ws + WS_PART_OFF);
        f32x4* payld  = (f32x4*)((char*)d_ws + WS_PAY_OFF);

        int pblocks = (TOTAL_PTS + 255) / 256;       // 1563
        zero_kernel<<<SCAN_BLOCKS, 256, 0, stream>>>(counts);
        hist_kernel<<<pblocks, 256, 0, stream>>>(gf, dimp, counts);
        scanA_kernel<<<SCAN_BLOCKS, 256, 0, stream>>>(counts, parts);
        scanB_kernel<<<1, 512, 0, stream>>>(parts);
        scanC_kernel<<<SCAN_BLOCKS, 256, 0, stream>>>(counts, parts);
        scatter_kernel<<<pblocks, 256, 0, stream>>>(gf, dimp, counts, payld);

        gather_sorted_pt<<<pblocks, 256, 0, stream>>>(img, payld, dimp, out);
    } else {
        int blocks = (TOTAL_OUT + 255) / 256;
        og_proj_direct<<<blocks, 256, 0, stream>>>(img, gf, dimp, out);
    }
}